// Round 8
// baseline (2424.872 us; speedup 1.0000x reference)
//
#include <hip/hip_runtime.h>
#include <hip/hip_bf16.h>

// ---------------------------------------------------------------------------
// LSTM_37847251812594: 2-layer LSTM (B=256, T=64, n_x=512, n_h=1024) + FC+softmax
// Round 8: deep register-staged B pipeline (T14), depth in VGPRs not LDS.
//   - B-operand: 8-chunk-deep reg pipeline (int4 loads, compiler emits counted
//     vmcnt), ds_write_b128 to swizzled pos, ds_read as round 7
//     -> up to 16 KB in flight per wave (was ~3 KB with 3-slot gload_lds ring)
//   - global side: quad-coalesced (lanes 4j..4j+3 cover one 64-B row);
//     LDS write/read use the same verified pos(r,k) involution (G21)
//   - 2 staging slots (parity, static idx under unroll-8; DS in-order per
//     wave makes same-iter write->read safe) + dedicated exchange slot
//   - weights LDS-resident, barrier/epilogue as round 7
// ---------------------------------------------------------------------------

typedef short  bf16x8 __attribute__((ext_vector_type(8)));
typedef float  f32x4  __attribute__((ext_vector_type(4)));
typedef int    int4v  __attribute__((ext_vector_type(4)));

#define NHID   1024
#define NBATCH 256
#define NBLK   256
#define HSZE   (NBATCH * NHID)

__device__ __forceinline__ unsigned short f2b(float f) {
    unsigned int u = __builtin_bit_cast(unsigned int, f);
    unsigned int r = (u + 0x7FFFu + ((u >> 16) & 1u)) >> 16;
    return (unsigned short)r;
}
__device__ __forceinline__ float sigmoidf_(float x) {
    return 1.0f / (1.0f + __expf(-x));
}
__device__ __forceinline__ float tanhf_(float x) {
    return 1.0f - 2.0f / (__expf(2.0f * x) + 1.0f);
}

// Transpose+convert: W[k][n] fp32 -> Wt[g][n][k] bf16, LDS-tiled 64x64.
__global__ __launch_bounds__(256)
void transpose_w_kernel(const float* __restrict__ w0, const float* __restrict__ w1,
                        const float* __restrict__ w2, const float* __restrict__ w3,
                        unsigned short* __restrict__ dst, int nv) {
    __shared__ unsigned short t[64][65];
    const int gate = blockIdx.z;
    const float* src = (gate == 0) ? w0 : (gate == 1) ? w1 : (gate == 2) ? w2 : w3;
    const int kt = blockIdx.x * 64;
    const int nt = blockIdx.y * 64;
    const int tid = threadIdx.x;
    const int rr = tid >> 6;
    const int cc = tid & 63;
    #pragma unroll
    for (int p = 0; p < 16; ++p) {
        const int row = p * 4 + rr;
        t[cc][row] = f2b(src[(size_t)(kt + row) * NHID + nt + cc]);
    }
    __syncthreads();
    #pragma unroll
    for (int p = 0; p < 16; ++p) {
        const int row = p * 4 + rr;
        dst[((size_t)gate * NHID + nt + row) * nv + kt + cc] = t[row][cc];
    }
}

__global__ void cvt_x_kernel(const float* __restrict__ x, unsigned short* __restrict__ xb, int total4) {
    int idx = blockIdx.x * 256 + threadIdx.x;
    if (idx < total4) {
        float4 v = reinterpret_cast<const float4*>(x)[idx];
        ushort4 o;
        o.x = f2b(v.x); o.y = f2b(v.y); o.z = f2b(v.z); o.w = f2b(v.w);
        reinterpret_cast<ushort4*>(xb)[idx] = o;
    }
}

// Two-level grid barrier (monotone counters, relaxed agent atomics,
// one release fence before arrive + one acquire fence after exit).
__device__ __forceinline__ void grid_sync(unsigned* bar, unsigned gen) {
    __syncthreads();
    if (threadIdx.x == 0) {
        __builtin_amdgcn_fence(__ATOMIC_RELEASE, "agent");
        unsigned* grp  = bar + (blockIdx.x & 7) * 16;
        unsigned* glob = bar + 128;
        unsigned* gctr = bar + 144;
        if (__hip_atomic_fetch_add(grp, 1u, __ATOMIC_RELAXED, __HIP_MEMORY_SCOPE_AGENT)
                == gen * 32u + 31u) {
            if (__hip_atomic_fetch_add(glob, 1u, __ATOMIC_RELAXED, __HIP_MEMORY_SCOPE_AGENT)
                    == gen * 8u + 7u) {
                __hip_atomic_store(gctr, gen + 1u, __ATOMIC_RELAXED, __HIP_MEMORY_SCOPE_AGENT);
            }
        }
        while (__hip_atomic_load(gctr, __ATOMIC_RELAXED, __HIP_MEMORY_SCOPE_AGENT) <= gen) {
            __builtin_amdgcn_s_sleep(2);
        }
        __builtin_amdgcn_fence(__ATOMIC_ACQUIRE, "agent");
    }
    __syncthreads();
}

// Persistent kernel: whole 64-step 2-layer recurrence.
// Block b owns rows r=0..15 (gate r>>2, hidden 4b+(r&3)) of both layers.
// LDS: [0,48K) L0 W, [48K,112K) L1 W, [112K,144K) 2 staging slots,
//      [144K,160K) exchange buffer.
__global__ __launch_bounds__(512)
void lstm_persist_kernel(const unsigned short* __restrict__ wt0,   // [4][1024][1536]
                         const unsigned short* __restrict__ wt1,   // [4][1024][2048]
                         const unsigned short* __restrict__ xb,    // [256][64][512]
                         const float* __restrict__ bf0, const float* __restrict__ bi0,
                         const float* __restrict__ bc0, const float* __restrict__ bo0,
                         const float* __restrict__ bf1, const float* __restrict__ bi1,
                         const float* __restrict__ bc1, const float* __restrict__ bo1,
                         unsigned short* __restrict__ h0b,   // [2][256][1024] bf16
                         unsigned short* __restrict__ h1b,   // [2][256][1024] bf16
                         float* __restrict__ h1f,            // [256][1024] fp32
                         unsigned* __restrict__ bar) {
    __shared__ __align__(16) char smem[163840];
    unsigned short* lw0 = (unsigned short*)smem;             // 48 KB
    unsigned short* lw1 = (unsigned short*)(smem + 49152);   // 64 KB
    char*           bufs = smem + 114688;                    // 2 x 16 KB staging
    float*          lx   = (float*)(smem + 147456);          // 16 KB exchange

    const int tid  = threadIdx.x;
    const int lane = tid & 63;
    const int w    = tid >> 6;     // wave 0..7 -> m rows [32w, 32w+32)
    const int c15  = lane & 15;
    const int kg   = lane >> 4;    // 0..3
    const int b    = blockIdx.x;
    const int bcol = b * 4;

    // ---- stage weights into LDS, fragment order [s][lane][8] ----
    {
        const int row = c15;                     // A-frag row = lane&15
        const int g   = row >> 2;
        const int hid = bcol + (row & 3);
        const unsigned short* s0 = wt0 + ((size_t)g * NHID + hid) * 1536 + kg * 8;
        #pragma unroll
        for (int i = 0; i < 6; ++i) {
            const int s = w + i * 8;
            *(bf16x8*)(lw0 + (size_t)(s * 64 + lane) * 8) = *(const bf16x8*)(s0 + s * 32);
        }
        const unsigned short* s1 = wt1 + ((size_t)g * NHID + hid) * 2048 + kg * 8;
        #pragma unroll
        for (int i = 0; i < 8; ++i) {
            const int s = w + i * 8;
            *(bf16x8*)(lw1 + (size_t)(s * 64 + lane) * 8) = *(const bf16x8*)(s1 + s * 32);
        }
    }

    // biases in registers (gate kg, hidden bcol+0..3)
    f32x4 bias0, bias1;
    {
        const float* bp0 = (kg == 0) ? bf0 : (kg == 1) ? bi0 : (kg == 2) ? bc0 : bo0;
        const float4 v = *(const float4*)(bp0 + bcol);
        bias0[0] = v.x; bias0[1] = v.y; bias0[2] = v.z; bias0[3] = v.w;
        const float* bp1 = (kg == 0) ? bf1 : (kg == 1) ? bi1 : (kg == 2) ? bc1 : bo1;
        const float4 u = *(const float4*)(bp1 + bcol);
        bias1[0] = u.x; bias1[1] = u.y; bias1[2] = u.z; bias1[3] = u.w;
    }
    __syncthreads();

    float c0s[4] = {0.f, 0.f, 0.f, 0.f};
    float c1s[4] = {0.f, 0.f, 0.f, 0.f};
    unsigned gen = 0;

    // Writer-side constants: lane holds fragment (row = lane>>2, koct = lane&3)
    // (quad-coalesced global read), stored to swizzled pos(r,k)=4r+((k+(r>>1))&3).
    const int    mr   = lane >> 2;
    const int    koct = lane & 3;
    const size_t colb = (size_t)koct * 16;
    const int    wpos = 4 * mr + ((koct + (mr >> 1)) & 3);
    // Reader-side: lane's fragment (row=lane&15, koct=lane>>4) at pos*16.
    const int bofs = (4 * (lane & 15) + (((lane >> 4) + ((lane >> 1) & 3)) & 3)) * 16;

    char* stripe0 = bufs + w * 2048;           // slot 0, this wave's stripe
    char* stripe1 = bufs + 16384 + w * 2048;   // slot 1

    // One layer-step: 4-gate GEMM (A from LDS weights, B via 8-deep reg
    // pipeline -> swizzled LDS slot) + LDS exchange + fused cell epilogue.
    auto layer = [&](const unsigned short* lw, int NC, int SH,
                     const unsigned short* bh_, const unsigned short* bx_, size_t xstr,
                     const f32x4& bias, float* cs,
                     unsigned short* hout, float* hfout) {
        const char* bh = (const char*)bh_;
        const char* bx = (const char*)bx_;
        f32x4 acc0 = bias, acc1 = bias;

        // row base pointers for this lane's two m-groups
        const char* bh0 = bh + (size_t)(w * 32 + mr) * 2048 + colb;
        const char* bh1 = bh + (size_t)(w * 32 + 16 + mr) * 2048 + colb;
        const char* bx0 = bx + (size_t)(w * 32 + mr) * xstr + colb;
        const char* bx1 = bx + (size_t)(w * 32 + 16 + mr) * xstr + colb;

        auto gaddr0 = [&](int c) -> const char* {
            return (c < SH) ? bh0 + (size_t)c * 64 : bx0 + (size_t)(c - SH) * 64;
        };
        auto gaddr1 = [&](int c) -> const char* {
            return (c < SH) ? bh1 + (size_t)c * 64 : bx1 + (size_t)(c - SH) * 64;
        };

        int4v ra[8], rb[8];
        #pragma unroll
        for (int i = 0; i < 8; ++i) {
            ra[i] = *(const int4v*)gaddr0(i);
            rb[i] = *(const int4v*)gaddr1(i);
        }

        #pragma unroll 8
        for (int c = 0; c < NC; ++c) {
            const int ri = c & 7;                       // static under unroll-8
            char* stripe = (c & 1) ? stripe1 : stripe0; // static under unroll-8
            // compiler inserts counted vmcnt for ra/rb[ri] here
            *(int4v*)(stripe + wpos * 16)        = ra[ri];
            *(int4v*)(stripe + 1024 + wpos * 16) = rb[ri];
            if (c + 8 < NC) {                           // refill depth-8 pipeline
                ra[ri] = *(const int4v*)gaddr0(c + 8);
                rb[ri] = *(const int4v*)gaddr1(c + 8);
            }
            // DS ops are in-order per wave: read-after-write of same slot safe
            const bf16x8 a  = *(const bf16x8*)(lw + ((size_t)c * 64 + lane) * 8);
            const bf16x8 b0 = *(const bf16x8*)(stripe + bofs);
            const bf16x8 b1 = *(const bf16x8*)(stripe + 1024 + bofs);
            acc0 = __builtin_amdgcn_mfma_f32_16x16x32_bf16(a, b0, acc0, 0, 0, 0);
            acc1 = __builtin_amdgcn_mfma_f32_16x16x32_bf16(a, b1, acc1, 0, 0, 0);
        }

        __syncthreads();
        // exchange: lane (kg,c15): D row = kg*4+j (gate kg, hidden j), col = m-32w
        float* lxw = lx + w * 512;
        #pragma unroll
        for (int j = 0; j < 4; ++j) {
            lxw[(kg * 4 + j) * 32 + c15]      = acc0[j];
            lxw[(kg * 4 + j) * 32 + 16 + c15] = acc1[j];
        }
        __syncthreads();
        // epilogue: thread t<256 owns m=t, all 4 hidden cells; packed 8-B store
        if (tid < 256) {
            const int w2  = tid >> 5;
            const int col = tid & 31;
            const float* L = lx + w2 * 512;
            float hv[4];
            #pragma unroll
            for (int hl = 0; hl < 4; ++hl) {
                const float fs = L[(0 * 4 + hl) * 32 + col];
                const float is = L[(1 * 4 + hl) * 32 + col];
                const float gs = L[(2 * 4 + hl) * 32 + col];
                const float os = L[(3 * 4 + hl) * 32 + col];
                const float fv = sigmoidf_(fs);
                const float iv = sigmoidf_(is);
                const float cv = tanhf_(gs);
                const float ov = sigmoidf_(os);
                const float cc = fv * cs[hl] + iv * cv;
                const float hh = ov * tanhf_(cc);
                cs[hl] = cc;
                hv[hl] = hh;
            }
            ushort4 hb;
            hb.x = f2b(hv[0]); hb.y = f2b(hv[1]); hb.z = f2b(hv[2]); hb.w = f2b(hv[3]);
            *reinterpret_cast<ushort4*>(hout + (size_t)tid * NHID + bcol) = hb;
            if (hfout) {
                float4 hf; hf.x = hv[0]; hf.y = hv[1]; hf.z = hv[2]; hf.w = hv[3];
                *reinterpret_cast<float4*>(hfout + (size_t)tid * NHID + bcol) = hf;
            }
        }
        __syncthreads();
    };

    // software pipeline: interval t does L0[t] and L1[t-1]; 1 grid barrier each
    for (int t = 0; t <= 64; ++t) {
        if (t < 64) {
            const unsigned short* hprev = h0b + (size_t)((t + 1) & 1) * HSZE;  // h0[t-1]
            unsigned short* hout        = h0b + (size_t)(t & 1) * HSZE;        // h0[t]
            layer(lw0, 48, 32, hprev, xb + (size_t)t * 512, (size_t)64 * 512 * 2,
                  bias0, c0s, hout, nullptr);
        }
        if (t >= 1) {
            const int u = t - 1;
            const unsigned short* h1prev = h1b + (size_t)((u + 1) & 1) * HSZE; // h1[u-1]
            const unsigned short* h0cur  = h0b + (size_t)(u & 1) * HSZE;       // h0[u]
            unsigned short* hout         = h1b + (size_t)(u & 1) * HSZE;       // h1[u]
            layer(lw1, 64, 32, h1prev, h0cur, (size_t)NHID * 2,
                  bias1, c1s, hout, (u == 63) ? h1f : nullptr);
        }
        if (t < 64) {
            grid_sync(bar, gen);
            ++gen;
        }
    }
}

// logits = h1 @ W + b : grid (4 n-blocks, 64 m-blocks), 4 m-rows staged in LDS.
__global__ __launch_bounds__(256)
void classifier_kernel(const float* __restrict__ h, const float* __restrict__ W,
                       const float* __restrict__ b, float* __restrict__ logits) {
    __shared__ float hs[4 * 1024];
    const int tid = threadIdx.x;
    const int m0 = blockIdx.y * 4;
    const int n  = blockIdx.x * 256 + tid;
    #pragma unroll
    for (int i = 0; i < 16; ++i)
        hs[i * 256 + tid] = h[(size_t)m0 * NHID + i * 256 + tid];
    __syncthreads();
    if (n < 1000) {
        float a0 = 0.f, a1 = 0.f, a2 = 0.f, a3 = 0.f;
        #pragma unroll 8
        for (int k = 0; k < NHID; ++k) {
            const float wv = W[(size_t)k * 1000 + n];
            a0 = fmaf(hs[k], wv, a0);
            a1 = fmaf(hs[1024 + k], wv, a1);
            a2 = fmaf(hs[2048 + k], wv, a2);
            a3 = fmaf(hs[3072 + k], wv, a3);
        }
        const float bv = b[n];
        logits[(size_t)(m0 + 0) * 1000 + n] = a0 + bv;
        logits[(size_t)(m0 + 1) * 1000 + n] = a1 + bv;
        logits[(size_t)(m0 + 2) * 1000 + n] = a2 + bv;
        logits[(size_t)(m0 + 3) * 1000 + n] = a3 + bv;
    }
}

__global__ void softmax_kernel(const float* __restrict__ logits, float* __restrict__ pred) {
    __shared__ float red[256];
    const int m = blockIdx.x;
    const int t = threadIdx.x;
    const float* lr = logits + (size_t)m * 1000;
    float mx = -3.4e38f;
    for (int i = t; i < 1000; i += 256) mx = fmaxf(mx, lr[i]);
    red[t] = mx; __syncthreads();
    for (int off = 128; off > 0; off >>= 1) {
        if (t < off) red[t] = fmaxf(red[t], red[t + off]);
        __syncthreads();
    }
    mx = red[0];
    __syncthreads();
    float sm = 0.0f;
    for (int i = t; i < 1000; i += 256) sm += __expf(lr[i] - mx);
    red[t] = sm; __syncthreads();
    for (int off = 128; off > 0; off >>= 1) {
        if (t < off) red[t] += red[t + off];
        __syncthreads();
    }
    const float inv = 1.0f / red[0];
    for (int i = t; i < 1000; i += 256)
        pred[(size_t)m * 1000 + i] = __expf(lr[i] - mx) * inv;
}

extern "C" void kernel_launch(void* const* d_in, const int* in_sizes, int n_in,
                              void* d_out, int out_size, void* d_ws, size_t ws_size,
                              hipStream_t stream) {
    (void)in_sizes; (void)n_in; (void)out_size; (void)ws_size;
    const float* x = (const float*)d_in[0];
    const float* W0[4] = {(const float*)d_in[1], (const float*)d_in[2], (const float*)d_in[3], (const float*)d_in[4]};
    const float* B0[4] = {(const float*)d_in[5], (const float*)d_in[6], (const float*)d_in[7], (const float*)d_in[8]};
    const float* W1[4] = {(const float*)d_in[9], (const float*)d_in[10], (const float*)d_in[11], (const float*)d_in[12]};
    const float* B1[4] = {(const float*)d_in[13], (const float*)d_in[14], (const float*)d_in[15], (const float*)d_in[16]};
    const float* Wc = (const float*)d_in[17];
    const float* bc = (const float*)d_in[18];
    float* out = (float*)d_out;

    char* ws = (char*)d_ws;
    size_t off = 0;
    auto alloc = [&](size_t bytes) -> char* {
        char* p = ws + off;
        off += (bytes + 255) & ~(size_t)255;
        return p;
    };
    unsigned short* wt0 = (unsigned short*)alloc((size_t)4 * NHID * 1536 * 2);
    unsigned short* wt1 = (unsigned short*)alloc((size_t)4 * NHID * 2048 * 2);
    unsigned short* xb  = (unsigned short*)alloc((size_t)NBATCH * 64 * 512 * 2);
    char* hstates = ws + off;
    unsigned short* h0b = (unsigned short*)alloc((size_t)2 * HSZE * 2);
    unsigned short* h1b = (unsigned short*)alloc((size_t)2 * HSZE * 2);
    size_t hstate_bytes = (size_t)((char*)h1b + (size_t)2 * HSZE * 2 - hstates);
    float* h1f = (float*)alloc((size_t)HSZE * 4);
    unsigned* bar = (unsigned*)alloc(1024);

    hipMemsetAsync(hstates, 0, hstate_bytes, stream);
    hipMemsetAsync(bar, 0, 1024, stream);

    transpose_w_kernel<<<dim3(1536 / 64, 16, 4), 256, 0, stream>>>(
        W0[0], W0[1], W0[2], W0[3], wt0, 1536);
    transpose_w_kernel<<<dim3(2048 / 64, 16, 4), 256, 0, stream>>>(
        W1[0], W1[1], W1[2], W1[3], wt1, 2048);
    cvt_x_kernel<<<(NBATCH * 64 * 512 / 4 + 255) / 256, 256, 0, stream>>>(
        x, xb, NBATCH * 64 * 512 / 4);

    lstm_persist_kernel<<<NBLK, 512, 0, stream>>>(
        wt0, wt1, xb,
        B0[0], B0[1], B0[2], B0[3],
        B1[0], B1[1], B1[2], B1[3],
        h0b, h1b, h1f, bar);

    classifier_kernel<<<dim3(4, 64), 256, 0, stream>>>(h1f, Wc, bc, out);
    softmax_kernel<<<NBATCH, 256, 0, stream>>>(out, out + (size_t)NBATCH * 1000);
}

// Round 9
// 2056.530 us; speedup vs baseline: 1.1791x; 1.1791x over previous
//
#include <hip/hip_runtime.h>
#include <hip/hip_bf16.h>

// ---------------------------------------------------------------------------
// LSTM_37847251812594: 2-layer LSTM (B=256, T=64, n_x=512, n_h=1024) + FC+softmax
// Round 9: B-operand direct global->VGPR in fragment-major layout + k-rotation.
//   - h/x stored FRAGMENT-MAJOR ([mg][chunk][lane][16B]): the MFMA B-fragment
//     load is one coalesced global_load_dwordx4 straight to registers.
//     B's LDS round-trip (write+read+staging) is GONE; LDS carries only
//     A-reads (~0.9 MB/CU/interval).
//   - per-block k-chunk rotation ((b>>3)&31): the 32 blocks of an XCD start
//     64 KB apart -> L2 banks served in parallel instead of lockstep-serial.
//   - epilogue writes h in fragment-major (same 8-B store); weights stay
//     LDS-resident; barrier as round 4.
// ---------------------------------------------------------------------------

typedef short  bf16x8 __attribute__((ext_vector_type(8)));
typedef float  f32x4  __attribute__((ext_vector_type(4)));

#define NHID   1024
#define NBATCH 256
#define NBLK   256
#define HSZE   (NBATCH * NHID)

__device__ __forceinline__ unsigned short f2b(float f) {
    unsigned int u = __builtin_bit_cast(unsigned int, f);
    unsigned int r = (u + 0x7FFFu + ((u >> 16) & 1u)) >> 16;
    return (unsigned short)r;
}
__device__ __forceinline__ float sigmoidf_(float x) {
    return 1.0f / (1.0f + __expf(-x));
}
__device__ __forceinline__ float tanhf_(float x) {
    return 1.0f - 2.0f / (__expf(2.0f * x) + 1.0f);
}

// Transpose+convert: W[k][n] fp32 -> Wt[g][n][k] bf16, LDS-tiled 64x64.
__global__ __launch_bounds__(256)
void transpose_w_kernel(const float* __restrict__ w0, const float* __restrict__ w1,
                        const float* __restrict__ w2, const float* __restrict__ w3,
                        unsigned short* __restrict__ dst, int nv) {
    __shared__ unsigned short t[64][65];
    const int gate = blockIdx.z;
    const float* src = (gate == 0) ? w0 : (gate == 1) ? w1 : (gate == 2) ? w2 : w3;
    const int kt = blockIdx.x * 64;
    const int nt = blockIdx.y * 64;
    const int tid = threadIdx.x;
    const int rr = tid >> 6;
    const int cc = tid & 63;
    #pragma unroll
    for (int p = 0; p < 16; ++p) {
        const int row = p * 4 + rr;
        t[cc][row] = f2b(src[(size_t)(kt + row) * NHID + nt + cc]);
    }
    __syncthreads();
    #pragma unroll
    for (int p = 0; p < 16; ++p) {
        const int row = p * 4 + rr;
        dst[((size_t)gate * NHID + nt + row) * nv + kt + cc] = t[row][cc];
    }
}

// x -> bf16, FRAGMENT-MAJOR per timestep:
// xb[t][mg][c][lane][8], lane = koct*16 + row, k = c*32 + koct*8 + e.
__global__ __launch_bounds__(256)
void cvt_x_frag_kernel(const float* __restrict__ x, unsigned short* __restrict__ xb) {
    const int t  = blockIdx.x;        // 0..63
    const int mg = blockIdx.y;        // 0..15
    const int g  = threadIdx.x >> 6;  // 0..3
    const int l  = threadIdx.x & 63;
    const int row = l & 15, ko = l >> 4;
    const float* src = x + (size_t)(mg * 16 + row) * 32768 + t * 512 + ko * 8;
    unsigned short* dst = xb + ((size_t)t * 256 * 512) + ((size_t)mg * 16 * 64 + l) * 8;
    #pragma unroll
    for (int i = 0; i < 4; ++i) {
        const int c = g * 4 + i;
        const float4 v0 = *(const float4*)(src + (size_t)c * 32);
        const float4 v1 = *(const float4*)(src + (size_t)c * 32 + 4);
        ushort4 o0, o1;
        o0.x = f2b(v0.x); o0.y = f2b(v0.y); o0.z = f2b(v0.z); o0.w = f2b(v0.w);
        o1.x = f2b(v1.x); o1.y = f2b(v1.y); o1.z = f2b(v1.z); o1.w = f2b(v1.w);
        *(ushort4*)(dst + (size_t)c * 512)     = o0;
        *(ushort4*)(dst + (size_t)c * 512 + 4) = o1;
    }
}

// Two-level grid barrier (monotone counters, relaxed agent atomics,
// one release fence before arrive + one acquire fence after exit).
__device__ __forceinline__ void grid_sync(unsigned* bar, unsigned gen) {
    __syncthreads();
    if (threadIdx.x == 0) {
        __builtin_amdgcn_fence(__ATOMIC_RELEASE, "agent");
        unsigned* grp  = bar + (blockIdx.x & 7) * 16;
        unsigned* glob = bar + 128;
        unsigned* gctr = bar + 144;
        if (__hip_atomic_fetch_add(grp, 1u, __ATOMIC_RELAXED, __HIP_MEMORY_SCOPE_AGENT)
                == gen * 32u + 31u) {
            if (__hip_atomic_fetch_add(glob, 1u, __ATOMIC_RELAXED, __HIP_MEMORY_SCOPE_AGENT)
                    == gen * 8u + 7u) {
                __hip_atomic_store(gctr, gen + 1u, __ATOMIC_RELAXED, __HIP_MEMORY_SCOPE_AGENT);
            }
        }
        while (__hip_atomic_load(gctr, __ATOMIC_RELAXED, __HIP_MEMORY_SCOPE_AGENT) <= gen) {
            __builtin_amdgcn_s_sleep(2);
        }
        __builtin_amdgcn_fence(__ATOMIC_ACQUIRE, "agent");
    }
    __syncthreads();
}

// Persistent kernel: whole 64-step 2-layer recurrence.
// Block b owns rows r=0..15 (gate r>>2, hidden 4b+(r&3)) of both layers.
// LDS: [0,48K) L0 W, [48K,112K) L1 W, [112K,128K) exchange.
// h buffers are fragment-major with C=32 chunks; xb C=16 per timestep.
__global__ __launch_bounds__(512)
void lstm_persist_kernel(const unsigned short* __restrict__ wt0,   // [4][1024][1536]
                         const unsigned short* __restrict__ wt1,   // [4][1024][2048]
                         const unsigned short* __restrict__ xb,    // frag-major [64][...]
                         const float* __restrict__ bf0, const float* __restrict__ bi0,
                         const float* __restrict__ bc0, const float* __restrict__ bo0,
                         const float* __restrict__ bf1, const float* __restrict__ bi1,
                         const float* __restrict__ bc1, const float* __restrict__ bo1,
                         unsigned short* __restrict__ h0b,   // [2] frag-major
                         unsigned short* __restrict__ h1b,   // [2] frag-major
                         float* __restrict__ h1f,            // [256][1024] fp32 plain
                         unsigned* __restrict__ bar) {
    __shared__ __align__(16) char smem[131072];
    unsigned short* lw0 = (unsigned short*)smem;             // 48 KB
    unsigned short* lw1 = (unsigned short*)(smem + 49152);   // 64 KB
    float*          lx  = (float*)(smem + 114688);           // 16 KB exchange

    const int tid  = threadIdx.x;
    const int lane = tid & 63;
    const int w    = tid >> 6;     // wave 0..7 -> m rows [32w, 32w+32)
    const int c15  = lane & 15;
    const int kg   = lane >> 4;    // 0..3
    const int b    = blockIdx.x;
    const int bcol = b * 4;

    // ---- stage weights into LDS, fragment order [s][lane][8] ----
    {
        const int row = c15;                     // A-frag row = lane&15
        const int g   = row >> 2;
        const int hid = bcol + (row & 3);
        const unsigned short* s0 = wt0 + ((size_t)g * NHID + hid) * 1536 + kg * 8;
        #pragma unroll
        for (int i = 0; i < 6; ++i) {
            const int s = w + i * 8;
            *(bf16x8*)(lw0 + (size_t)(s * 64 + lane) * 8) = *(const bf16x8*)(s0 + s * 32);
        }
        const unsigned short* s1 = wt1 + ((size_t)g * NHID + hid) * 2048 + kg * 8;
        #pragma unroll
        for (int i = 0; i < 8; ++i) {
            const int s = w + i * 8;
            *(bf16x8*)(lw1 + (size_t)(s * 64 + lane) * 8) = *(const bf16x8*)(s1 + s * 32);
        }
    }

    // biases in registers (gate kg, hidden bcol+0..3)
    f32x4 bias0, bias1;
    {
        const float* bp0 = (kg == 0) ? bf0 : (kg == 1) ? bi0 : (kg == 2) ? bc0 : bo0;
        const float4 v = *(const float4*)(bp0 + bcol);
        bias0[0] = v.x; bias0[1] = v.y; bias0[2] = v.z; bias0[3] = v.w;
        const float* bp1 = (kg == 0) ? bf1 : (kg == 1) ? bi1 : (kg == 2) ? bc1 : bo1;
        const float4 u = *(const float4*)(bp1 + bcol);
        bias1[0] = u.x; bias1[1] = u.y; bias1[2] = u.z; bias1[3] = u.w;
    }
    __syncthreads();

    float c0s[4] = {0.f, 0.f, 0.f, 0.f};
    float c1s[4] = {0.f, 0.f, 0.f, 0.f};
    unsigned gen = 0;

    // k-chunk rotation: the 32 blocks of one XCD (b = xcd + 8j) get distinct
    // start chunks -> no lockstep same-line L2 requests.
    const int rot32 = (b >> 3) & 31;
    const int rot16 = (b >> 3) & 15;

    // epilogue h-write position (fragment-major), constants per thread
    const int ch_w  = bcol >> 5;          // chunk of this block's 4 hidden units
    const int ko_w  = (bcol >> 3) & 3;    // k-oct
    const int e0_w  = bcol & 7;           // element within oct (0 or 4)
    const size_t hoff = (((size_t)(tid >> 4) * 32 + ch_w) * 64 + ko_w * 16 + (tid & 15)) * 8 + e0_w;

    // One layer-step. A from LDS weights; B direct global->VGPR, fragment-major.
    // SH=32 h-chunks (rot_h), NX x-chunks (rot_x); A-chunk for x-part = SH+cc.
    auto layer = [&](const unsigned short* lw, const int NX,
                     const int rot_h, const int rot_x,
                     const unsigned short* bh, const unsigned short* bx,
                     const f32x4& bias, float* cs,
                     unsigned short* hout, float* hfout) {
        f32x4 acc0 = bias, acc1 = bias;
        const unsigned short* ph0 = bh + ((size_t)(2 * w)     * 32 * 64 + lane) * 8;
        const unsigned short* ph1 = bh + ((size_t)(2 * w + 1) * 32 * 64 + lane) * 8;
        const unsigned short* px0 = bx + ((size_t)(2 * w)     * NX * 64 + lane) * 8;
        const unsigned short* px1 = bx + ((size_t)(2 * w + 1) * NX * 64 + lane) * 8;

        #pragma unroll 8
        for (int i = 0; i < 32 - rot_h; ++i) {
            const int cc = rot_h + i;
            const bf16x8 a  = *(const bf16x8*)(lw + ((size_t)cc * 64 + lane) * 8);
            const bf16x8 b0 = *(const bf16x8*)(ph0 + (size_t)cc * 512);
            const bf16x8 b1 = *(const bf16x8*)(ph1 + (size_t)cc * 512);
            acc0 = __builtin_amdgcn_mfma_f32_16x16x32_bf16(a, b0, acc0, 0, 0, 0);
            acc1 = __builtin_amdgcn_mfma_f32_16x16x32_bf16(a, b1, acc1, 0, 0, 0);
        }
        #pragma unroll 8
        for (int cc = 0; cc < rot_h; ++cc) {
            const bf16x8 a  = *(const bf16x8*)(lw + ((size_t)cc * 64 + lane) * 8);
            const bf16x8 b0 = *(const bf16x8*)(ph0 + (size_t)cc * 512);
            const bf16x8 b1 = *(const bf16x8*)(ph1 + (size_t)cc * 512);
            acc0 = __builtin_amdgcn_mfma_f32_16x16x32_bf16(a, b0, acc0, 0, 0, 0);
            acc1 = __builtin_amdgcn_mfma_f32_16x16x32_bf16(a, b1, acc1, 0, 0, 0);
        }
        #pragma unroll 8
        for (int i = 0; i < NX - rot_x; ++i) {
            const int cc = rot_x + i;
            const bf16x8 a  = *(const bf16x8*)(lw + ((size_t)(32 + cc) * 64 + lane) * 8);
            const bf16x8 b0 = *(const bf16x8*)(px0 + (size_t)cc * 512);
            const bf16x8 b1 = *(const bf16x8*)(px1 + (size_t)cc * 512);
            acc0 = __builtin_amdgcn_mfma_f32_16x16x32_bf16(a, b0, acc0, 0, 0, 0);
            acc1 = __builtin_amdgcn_mfma_f32_16x16x32_bf16(a, b1, acc1, 0, 0, 0);
        }
        #pragma unroll 8
        for (int cc = 0; cc < rot_x; ++cc) {
            const bf16x8 a  = *(const bf16x8*)(lw + ((size_t)(32 + cc) * 64 + lane) * 8);
            const bf16x8 b0 = *(const bf16x8*)(px0 + (size_t)cc * 512);
            const bf16x8 b1 = *(const bf16x8*)(px1 + (size_t)cc * 512);
            acc0 = __builtin_amdgcn_mfma_f32_16x16x32_bf16(a, b0, acc0, 0, 0, 0);
            acc1 = __builtin_amdgcn_mfma_f32_16x16x32_bf16(a, b1, acc1, 0, 0, 0);
        }

        __syncthreads();
        // exchange: lane (kg,c15): D row = kg*4+j (gate kg, hidden j), col = m-32w
        float* lxw = lx + w * 512;
        #pragma unroll
        for (int j = 0; j < 4; ++j) {
            lxw[(kg * 4 + j) * 32 + c15]      = acc0[j];
            lxw[(kg * 4 + j) * 32 + 16 + c15] = acc1[j];
        }
        __syncthreads();
        // epilogue: thread t<256 owns m=t, all 4 hidden cells; 8-B frag-major store
        if (tid < 256) {
            const int w2  = tid >> 5;
            const int col = tid & 31;
            const float* L = lx + w2 * 512;
            float hv[4];
            #pragma unroll
            for (int hl = 0; hl < 4; ++hl) {
                const float fs = L[(0 * 4 + hl) * 32 + col];
                const float is = L[(1 * 4 + hl) * 32 + col];
                const float gs = L[(2 * 4 + hl) * 32 + col];
                const float os = L[(3 * 4 + hl) * 32 + col];
                const float fv = sigmoidf_(fs);
                const float iv = sigmoidf_(is);
                const float cv = tanhf_(gs);
                const float ov = sigmoidf_(os);
                const float cc = fv * cs[hl] + iv * cv;
                const float hh = ov * tanhf_(cc);
                cs[hl] = cc;
                hv[hl] = hh;
            }
            ushort4 hb;
            hb.x = f2b(hv[0]); hb.y = f2b(hv[1]); hb.z = f2b(hv[2]); hb.w = f2b(hv[3]);
            *reinterpret_cast<ushort4*>(hout + hoff) = hb;
            if (hfout) {
                float4 hf; hf.x = hv[0]; hf.y = hv[1]; hf.z = hv[2]; hf.w = hv[3];
                *reinterpret_cast<float4*>(hfout + (size_t)tid * NHID + bcol) = hf;
            }
        }
        __syncthreads();
    };

    // software pipeline: interval t does L0[t] and L1[t-1]; 1 grid barrier each
    for (int t = 0; t <= 64; ++t) {
        if (t < 64) {
            const unsigned short* hprev = h0b + (size_t)((t + 1) & 1) * HSZE;  // h0[t-1]
            unsigned short* hout        = h0b + (size_t)(t & 1) * HSZE;        // h0[t]
            layer(lw0, 16, rot32, rot16, hprev, xb + (size_t)t * 256 * 512,
                  bias0, c0s, hout, nullptr);
        }
        if (t >= 1) {
            const int u = t - 1;
            const unsigned short* h1prev = h1b + (size_t)((u + 1) & 1) * HSZE; // h1[u-1]
            const unsigned short* h0cur  = h0b + (size_t)(u & 1) * HSZE;       // h0[u]
            unsigned short* hout         = h1b + (size_t)(u & 1) * HSZE;       // h1[u]
            layer(lw1, 32, rot32, rot32, h1prev, h0cur,
                  bias1, c1s, hout, (u == 63) ? h1f : nullptr);
        }
        if (t < 64) {
            grid_sync(bar, gen);
            ++gen;
        }
    }
}

// logits = h1 @ W + b : grid (4 n-blocks, 64 m-blocks), 4 m-rows staged in LDS.
__global__ __launch_bounds__(256)
void classifier_kernel(const float* __restrict__ h, const float* __restrict__ W,
                       const float* __restrict__ b, float* __restrict__ logits) {
    __shared__ float hs[4 * 1024];
    const int tid = threadIdx.x;
    const int m0 = blockIdx.y * 4;
    const int n  = blockIdx.x * 256 + tid;
    #pragma unroll
    for (int i = 0; i < 16; ++i)
        hs[i * 256 + tid] = h[(size_t)m0 * NHID + i * 256 + tid];
    __syncthreads();
    if (n < 1000) {
        float a0 = 0.f, a1 = 0.f, a2 = 0.f, a3 = 0.f;
        #pragma unroll 8
        for (int k = 0; k < NHID; ++k) {
            const float wv = W[(size_t)k * 1000 + n];
            a0 = fmaf(hs[k], wv, a0);
            a1 = fmaf(hs[1024 + k], wv, a1);
            a2 = fmaf(hs[2048 + k], wv, a2);
            a3 = fmaf(hs[3072 + k], wv, a3);
        }
        const float bv = b[n];
        logits[(size_t)(m0 + 0) * 1000 + n] = a0 + bv;
        logits[(size_t)(m0 + 1) * 1000 + n] = a1 + bv;
        logits[(size_t)(m0 + 2) * 1000 + n] = a2 + bv;
        logits[(size_t)(m0 + 3) * 1000 + n] = a3 + bv;
    }
}

__global__ void softmax_kernel(const float* __restrict__ logits, float* __restrict__ pred) {
    __shared__ float red[256];
    const int m = blockIdx.x;
    const int t = threadIdx.x;
    const float* lr = logits + (size_t)m * 1000;
    float mx = -3.4e38f;
    for (int i = t; i < 1000; i += 256) mx = fmaxf(mx, lr[i]);
    red[t] = mx; __syncthreads();
    for (int off = 128; off > 0; off >>= 1) {
        if (t < off) red[t] = fmaxf(red[t], red[t + off]);
        __syncthreads();
    }
    mx = red[0];
    __syncthreads();
    float sm = 0.0f;
    for (int i = t; i < 1000; i += 256) sm += __expf(lr[i] - mx);
    red[t] = sm; __syncthreads();
    for (int off = 128; off > 0; off >>= 1) {
        if (t < off) red[t] += red[t + off];
        __syncthreads();
    }
    const float inv = 1.0f / red[0];
    for (int i = t; i < 1000; i += 256)
        pred[(size_t)m * 1000 + i] = __expf(lr[i] - mx) * inv;
}

extern "C" void kernel_launch(void* const* d_in, const int* in_sizes, int n_in,
                              void* d_out, int out_size, void* d_ws, size_t ws_size,
                              hipStream_t stream) {
    (void)in_sizes; (void)n_in; (void)out_size; (void)ws_size;
    const float* x = (const float*)d_in[0];
    const float* W0[4] = {(const float*)d_in[1], (const float*)d_in[2], (const float*)d_in[3], (const float*)d_in[4]};
    const float* B0[4] = {(const float*)d_in[5], (const float*)d_in[6], (const float*)d_in[7], (const float*)d_in[8]};
    const float* W1[4] = {(const float*)d_in[9], (const float*)d_in[10], (const float*)d_in[11], (const float*)d_in[12]};
    const float* B1[4] = {(const float*)d_in[13], (const float*)d_in[14], (const float*)d_in[15], (const float*)d_in[16]};
    const float* Wc = (const float*)d_in[17];
    const float* bc = (const float*)d_in[18];
    float* out = (float*)d_out;

    char* ws = (char*)d_ws;
    size_t off = 0;
    auto alloc = [&](size_t bytes) -> char* {
        char* p = ws + off;
        off += (bytes + 255) & ~(size_t)255;
        return p;
    };
    unsigned short* wt0 = (unsigned short*)alloc((size_t)4 * NHID * 1536 * 2);
    unsigned short* wt1 = (unsigned short*)alloc((size_t)4 * NHID * 2048 * 2);
    unsigned short* xb  = (unsigned short*)alloc((size_t)NBATCH * 64 * 512 * 2);
    char* hstates = ws + off;
    unsigned short* h0b = (unsigned short*)alloc((size_t)2 * HSZE * 2);
    unsigned short* h1b = (unsigned short*)alloc((size_t)2 * HSZE * 2);
    size_t hstate_bytes = (size_t)((char*)h1b + (size_t)2 * HSZE * 2 - hstates);
    float* h1f = (float*)alloc((size_t)HSZE * 4);
    unsigned* bar = (unsigned*)alloc(1024);

    hipMemsetAsync(hstates, 0, hstate_bytes, stream);
    hipMemsetAsync(bar, 0, 1024, stream);

    transpose_w_kernel<<<dim3(1536 / 64, 16, 4), 256, 0, stream>>>(
        W0[0], W0[1], W0[2], W0[3], wt0, 1536);
    transpose_w_kernel<<<dim3(2048 / 64, 16, 4), 256, 0, stream>>>(
        W1[0], W1[1], W1[2], W1[3], wt1, 2048);
    cvt_x_frag_kernel<<<dim3(64, 16), 256, 0, stream>>>(x, xb);

    lstm_persist_kernel<<<NBLK, 512, 0, stream>>>(
        wt0, wt1, xb,
        B0[0], B0[1], B0[2], B0[3],
        B1[0], B1[1], B1[2], B1[3],
        h0b, h1b, h1f, bar);

    classifier_kernel<<<dim3(4, 64), 256, 0, stream>>>(h1f, Wc, bc, out);
    softmax_kernel<<<NBATCH, 256, 0, stream>>>(out, out + (size_t)NBATCH * 1000);
}

// Round 10
// 1488.425 us; speedup vs baseline: 1.6292x; 1.3817x over previous
//
#include <hip/hip_runtime.h>
#include <hip/hip_bf16.h>

// ---------------------------------------------------------------------------
// LSTM_37847251812594: 2-layer LSTM (B=256, T=64, n_x=512, n_h=1024) + FC+softmax
// Round 10: layer-split persistent kernel.
//   - blocks split by layer ((b>>3)&1): 128 blocks own layer 0, 128 own layer 1;
//     each block owns 8 hidden units (32 gate-rows) of ITS layer only.
//     -> B-broadcast per block halves (768KB/1MB vs 1.78MB), and the two
//        layer-steps of an interval run on DIFFERENT CUs (max, not sum).
//   - weights LDS-resident: L0 96 KB, L1 128 KB (2 row-tiles x K chunks).
//   - epilogue without LDS: lane l and l^32 hold complementary gate pairs
//     (F,C vs I,O) for the same (hidden,m) -> 16 __shfl_xor, no exchange
//     buffer, no per-step __syncthreads; all 512 threads update 4 cells.
//   - frag-major h/x, k-rotation, grid barrier as round 9.
// ---------------------------------------------------------------------------

typedef short  bf16x8 __attribute__((ext_vector_type(8)));
typedef float  f32x4  __attribute__((ext_vector_type(4)));

#define NHID   1024
#define NBATCH 256
#define NBLK   256
#define HSZE   (NBATCH * NHID)

__device__ __forceinline__ unsigned short f2b(float f) {
    unsigned int u = __builtin_bit_cast(unsigned int, f);
    unsigned int r = (u + 0x7FFFu + ((u >> 16) & 1u)) >> 16;
    return (unsigned short)r;
}
__device__ __forceinline__ float sigmoidf_(float x) {
    return 1.0f / (1.0f + __expf(-x));
}
__device__ __forceinline__ float tanhf_(float x) {
    return 1.0f - 2.0f / (__expf(2.0f * x) + 1.0f);
}

// Transpose+convert: W[k][n] fp32 -> Wt[g][n][k] bf16, LDS-tiled 64x64.
__global__ __launch_bounds__(256)
void transpose_w_kernel(const float* __restrict__ w0, const float* __restrict__ w1,
                        const float* __restrict__ w2, const float* __restrict__ w3,
                        unsigned short* __restrict__ dst, int nv) {
    __shared__ unsigned short t[64][65];
    const int gate = blockIdx.z;
    const float* src = (gate == 0) ? w0 : (gate == 1) ? w1 : (gate == 2) ? w2 : w3;
    const int kt = blockIdx.x * 64;
    const int nt = blockIdx.y * 64;
    const int tid = threadIdx.x;
    const int rr = tid >> 6;
    const int cc = tid & 63;
    #pragma unroll
    for (int p = 0; p < 16; ++p) {
        const int row = p * 4 + rr;
        t[cc][row] = f2b(src[(size_t)(kt + row) * NHID + nt + cc]);
    }
    __syncthreads();
    #pragma unroll
    for (int p = 0; p < 16; ++p) {
        const int row = p * 4 + rr;
        dst[((size_t)gate * NHID + nt + row) * nv + kt + cc] = t[row][cc];
    }
}

// x -> bf16, FRAGMENT-MAJOR per timestep:
// xb[t][mg][c][lane][8], lane = koct*16 + row, k = c*32 + koct*8 + e.
__global__ __launch_bounds__(256)
void cvt_x_frag_kernel(const float* __restrict__ x, unsigned short* __restrict__ xb) {
    const int t  = blockIdx.x;        // 0..63
    const int mg = blockIdx.y;        // 0..15
    const int g  = threadIdx.x >> 6;  // 0..3
    const int l  = threadIdx.x & 63;
    const int row = l & 15, ko = l >> 4;
    const float* src = x + (size_t)(mg * 16 + row) * 32768 + t * 512 + ko * 8;
    unsigned short* dst = xb + ((size_t)t * 256 * 512) + ((size_t)mg * 16 * 64 + l) * 8;
    #pragma unroll
    for (int i = 0; i < 4; ++i) {
        const int c = g * 4 + i;
        const float4 v0 = *(const float4*)(src + (size_t)c * 32);
        const float4 v1 = *(const float4*)(src + (size_t)c * 32 + 4);
        ushort4 o0, o1;
        o0.x = f2b(v0.x); o0.y = f2b(v0.y); o0.z = f2b(v0.z); o0.w = f2b(v0.w);
        o1.x = f2b(v1.x); o1.y = f2b(v1.y); o1.z = f2b(v1.z); o1.w = f2b(v1.w);
        *(ushort4*)(dst + (size_t)c * 512)     = o0;
        *(ushort4*)(dst + (size_t)c * 512 + 4) = o1;
    }
}

// Two-level grid barrier (monotone counters, relaxed agent atomics,
// one release fence before arrive + one acquire fence after exit).
__device__ __forceinline__ void grid_sync(unsigned* bar, unsigned gen) {
    __syncthreads();
    if (threadIdx.x == 0) {
        __builtin_amdgcn_fence(__ATOMIC_RELEASE, "agent");
        unsigned* grp  = bar + (blockIdx.x & 7) * 16;
        unsigned* glob = bar + 128;
        unsigned* gctr = bar + 144;
        if (__hip_atomic_fetch_add(grp, 1u, __ATOMIC_RELAXED, __HIP_MEMORY_SCOPE_AGENT)
                == gen * 32u + 31u) {
            if (__hip_atomic_fetch_add(glob, 1u, __ATOMIC_RELAXED, __HIP_MEMORY_SCOPE_AGENT)
                    == gen * 8u + 7u) {
                __hip_atomic_store(gctr, gen + 1u, __ATOMIC_RELAXED, __HIP_MEMORY_SCOPE_AGENT);
            }
        }
        while (__hip_atomic_load(gctr, __ATOMIC_RELAXED, __HIP_MEMORY_SCOPE_AGENT) <= gen) {
            __builtin_amdgcn_s_sleep(2);
        }
        __builtin_amdgcn_fence(__ATOMIC_ACQUIRE, "agent");
    }
    __syncthreads();
}

// Persistent kernel, layer-split.
// layer = (b>>3)&1; lb = (b>>4)*8 + (b&7) in [0,128).
// Block owns hidden [8*lb, 8*lb+8) of its layer: 32 gate-rows =
// 2 MFMA row-tiles (rt0: F,I ; rt1: C,O), row R: gate=R>>3, hl=R&7.
// LDS: lw[c][rt][lane][8] bf16 (L0: 48 chunks=96KB, L1: 64=128KB). No exchange.
__global__ __launch_bounds__(512)
void lstm_persist_kernel(const unsigned short* __restrict__ wt0,   // [4][1024][1536]
                         const unsigned short* __restrict__ wt1,   // [4][1024][2048]
                         const unsigned short* __restrict__ xb,    // frag-major [64][...]
                         const float* __restrict__ bf0, const float* __restrict__ bi0,
                         const float* __restrict__ bc0, const float* __restrict__ bo0,
                         const float* __restrict__ bf1, const float* __restrict__ bi1,
                         const float* __restrict__ bc1, const float* __restrict__ bo1,
                         unsigned short* __restrict__ h0b,   // [2] frag-major
                         unsigned short* __restrict__ h1b,   // [2] frag-major
                         float* __restrict__ h1f,            // [256][1024] fp32 plain
                         unsigned* __restrict__ bar) {
    __shared__ __align__(16) unsigned short lw[65536];   // up to 128 KB

    const int tid  = threadIdx.x;
    const int lane = tid & 63;
    const int w    = tid >> 6;     // wave 0..7 -> m rows [32w, 32w+32)
    const int c15  = lane & 15;
    const int kg   = lane >> 4;    // 0..3
    const int b    = blockIdx.x;
    const int layer = (b >> 3) & 1;
    const int lb    = ((b >> 4) << 3) | (b & 7);   // 0..127 within layer

    const unsigned short* wt = layer ? wt1 : wt0;
    const int NV  = layer ? 2048 : 1536;
    const int NCW = NV >> 5;            // 48 or 64 chunks
    const int NX  = layer ? 32 : 16;    // x-part chunks

    // ---- stage this block's 32 gate-rows into LDS, fragment order ----
    #pragma unroll
    for (int i = 0; i < 8; ++i) {
        const int c = w + i * 8;
        if (c < NCW) {
            #pragma unroll
            for (int rt = 0; rt < 2; ++rt) {
                const int R   = rt * 16 + c15;
                const int g   = R >> 3;
                const int hid = 8 * lb + (R & 7);
                const int k   = c * 32 + kg * 8;
                *(bf16x8*)(lw + ((size_t)(c * 2 + rt) * 64 + lane) * 8) =
                    *(const bf16x8*)(wt + ((size_t)g * NHID + hid) * NV + k);
            }
        }
    }

    // biases: biasv[rt][j] for row R = rt*16 + kg*4 + j
    f32x4 biasv[2];
    {
        const float* bp[4];
        if (layer) { bp[0] = bf1; bp[1] = bi1; bp[2] = bc1; bp[3] = bo1; }
        else       { bp[0] = bf0; bp[1] = bi0; bp[2] = bc0; bp[3] = bo0; }
        #pragma unroll
        for (int rt = 0; rt < 2; ++rt)
            #pragma unroll
            for (int j = 0; j < 4; ++j) {
                const int R = rt * 16 + kg * 4 + j;
                biasv[rt][j] = bp[R >> 3][8 * lb + (R & 7)];
            }
    }
    __syncthreads();

    float cs[4] = {0.f, 0.f, 0.f, 0.f};   // 4 cells per thread (m=mrow, hl=eb..eb+3)
    unsigned gen = 0;

    const int rot_h = (b >> 3) & 31;
    const int rot_x = layer ? rot_h : ((b >> 4) & 15);
    const bool hiM  = (kg >= 2);

    // h-write position (frag-major): hidden k = 8*lb + eb..eb+3 is half of k-oct lb
    const int chw = lb >> 2, kow = lb & 3, eb = (kg & 1) * 4;
    const int mg   = 2 * w + (hiM ? 1 : 0);
    const int mrow = 32 * w + (hiM ? 16 : 0) + c15;
    const size_t hoff = (((size_t)mg * 32 + chw) * 64 + kow * 16 + c15) * 8 + eb;

    auto step = [&](const unsigned short* bh, const unsigned short* bx,
                    unsigned short* hout, float* hfout) {
        f32x4 a00 = biasv[0], a01 = biasv[0];   // rt0 x {mf0, mf1}
        f32x4 a10 = biasv[1], a11 = biasv[1];   // rt1 x {mf0, mf1}
        const unsigned short* ph0 = bh + ((size_t)(2 * w)     * 32 * 64 + lane) * 8;
        const unsigned short* ph1 = bh + ((size_t)(2 * w + 1) * 32 * 64 + lane) * 8;
        const unsigned short* px0 = bx + ((size_t)(2 * w)     * NX * 64 + lane) * 8;
        const unsigned short* px1 = bx + ((size_t)(2 * w + 1) * NX * 64 + lane) * 8;

        #pragma unroll 8
        for (int i = 0; i < 32; ++i) {
            const int cc = (i + rot_h) & 31;
            const bf16x8 va0 = *(const bf16x8*)(lw + ((size_t)(cc * 2)     * 64 + lane) * 8);
            const bf16x8 va1 = *(const bf16x8*)(lw + ((size_t)(cc * 2 + 1) * 64 + lane) * 8);
            const bf16x8 vb0 = *(const bf16x8*)(ph0 + (size_t)cc * 512);
            const bf16x8 vb1 = *(const bf16x8*)(ph1 + (size_t)cc * 512);
            a00 = __builtin_amdgcn_mfma_f32_16x16x32_bf16(va0, vb0, a00, 0, 0, 0);
            a01 = __builtin_amdgcn_mfma_f32_16x16x32_bf16(va0, vb1, a01, 0, 0, 0);
            a10 = __builtin_amdgcn_mfma_f32_16x16x32_bf16(va1, vb0, a10, 0, 0, 0);
            a11 = __builtin_amdgcn_mfma_f32_16x16x32_bf16(va1, vb1, a11, 0, 0, 0);
        }
        #pragma unroll 8
        for (int i = 0; i < NX; ++i) {
            const int cc = (i + rot_x) & (NX - 1);
            const bf16x8 va0 = *(const bf16x8*)(lw + ((size_t)((32 + cc) * 2)     * 64 + lane) * 8);
            const bf16x8 va1 = *(const bf16x8*)(lw + ((size_t)((32 + cc) * 2 + 1) * 64 + lane) * 8);
            const bf16x8 vb0 = *(const bf16x8*)(px0 + (size_t)cc * 512);
            const bf16x8 vb1 = *(const bf16x8*)(px1 + (size_t)cc * 512);
            a00 = __builtin_amdgcn_mfma_f32_16x16x32_bf16(va0, vb0, a00, 0, 0, 0);
            a01 = __builtin_amdgcn_mfma_f32_16x16x32_bf16(va0, vb1, a01, 0, 0, 0);
            a10 = __builtin_amdgcn_mfma_f32_16x16x32_bf16(va1, vb0, a10, 0, 0, 0);
            a11 = __builtin_amdgcn_mfma_f32_16x16x32_bf16(va1, vb1, a11, 0, 0, 0);
        }

        // cross-lane gate exchange: lane l <-> l^32 hold complementary gates
        // (rt0: F for kg<2, I for kg>=2; rt1: C / O) for the SAME (hl, m).
        // Lane handles m-frag mf = hiM; partner's same-mf acc completes its 4 gates.
        f32x4 r0, r1;   // partner's (rt0, rt1) acc for MY m-frag
        #pragma unroll
        for (int j = 0; j < 4; ++j) {
            const float s0 = hiM ? a01[j] : a00[j];
            const float s1 = hiM ? a11[j] : a10[j];
            // shfl both mf variants; each lane keeps the one matching its mf
            const float t0 = __shfl_xor(a00[j], 32);
            const float t1 = __shfl_xor(a01[j], 32);
            const float t2 = __shfl_xor(a10[j], 32);
            const float t3 = __shfl_xor(a11[j], 32);
            r0[j] = hiM ? t1 : t0;
            r1[j] = hiM ? t3 : t2;
            (void)s0; (void)s1;
        }
        const f32x4 own0 = hiM ? a01 : a00;
        const f32x4 own1 = hiM ? a11 : a10;

        ushort4 hb;
        float4  hf;
        float hv[4];
        #pragma unroll
        for (int j = 0; j < 4; ++j) {
            const float fsv = hiM ? r0[j]   : own0[j];
            const float isv = hiM ? own0[j] : r0[j];
            const float csv = hiM ? r1[j]   : own1[j];
            const float osv = hiM ? own1[j] : r1[j];
            const float fv = sigmoidf_(fsv);
            const float iv = sigmoidf_(isv);
            const float cv = tanhf_(csv);
            const float ov = sigmoidf_(osv);
            const float ccv = fv * cs[j] + iv * cv;
            const float hh  = ov * tanhf_(ccv);
            cs[j] = ccv;
            hv[j] = hh;
        }
        hb.x = f2b(hv[0]); hb.y = f2b(hv[1]); hb.z = f2b(hv[2]); hb.w = f2b(hv[3]);
        *reinterpret_cast<ushort4*>(hout + hoff) = hb;
        if (hfout) {
            hf.x = hv[0]; hf.y = hv[1]; hf.z = hv[2]; hf.w = hv[3];
            *reinterpret_cast<float4*>(hfout + (size_t)mrow * NHID + 8 * lb + eb) = hf;
        }
    };

    // pipeline: interval t: L0-blocks do L0[t], L1-blocks do L1[t-1]; 1 barrier
    for (int t = 0; t <= 64; ++t) {
        if (layer == 0) {
            if (t < 64) {
                step(h0b + (size_t)((t + 1) & 1) * HSZE,
                     xb + (size_t)t * 256 * 512,
                     h0b + (size_t)(t & 1) * HSZE, nullptr);
            }
        } else {
            if (t >= 1) {
                const int u = t - 1;
                step(h1b + (size_t)((u + 1) & 1) * HSZE,
                     h0b + (size_t)(u & 1) * HSZE,
                     h1b + (size_t)(u & 1) * HSZE,
                     (u == 63) ? h1f : nullptr);
            }
        }
        if (t < 64) {
            grid_sync(bar, gen);
            ++gen;
        }
    }
}

// logits = h1 @ W + b : grid (4 n-blocks, 64 m-blocks), 4 m-rows staged in LDS.
__global__ __launch_bounds__(256)
void classifier_kernel(const float* __restrict__ h, const float* __restrict__ W,
                       const float* __restrict__ b, float* __restrict__ logits) {
    __shared__ float hs[4 * 1024];
    const int tid = threadIdx.x;
    const int m0 = blockIdx.y * 4;
    const int n  = blockIdx.x * 256 + tid;
    #pragma unroll
    for (int i = 0; i < 16; ++i)
        hs[i * 256 + tid] = h[(size_t)m0 * NHID + i * 256 + tid];
    __syncthreads();
    if (n < 1000) {
        float a0 = 0.f, a1 = 0.f, a2 = 0.f, a3 = 0.f;
        #pragma unroll 8
        for (int k = 0; k < NHID; ++k) {
            const float wv = W[(size_t)k * 1000 + n];
            a0 = fmaf(hs[k], wv, a0);
            a1 = fmaf(hs[1024 + k], wv, a1);
            a2 = fmaf(hs[2048 + k], wv, a2);
            a3 = fmaf(hs[3072 + k], wv, a3);
        }
        const float bv = b[n];
        logits[(size_t)(m0 + 0) * 1000 + n] = a0 + bv;
        logits[(size_t)(m0 + 1) * 1000 + n] = a1 + bv;
        logits[(size_t)(m0 + 2) * 1000 + n] = a2 + bv;
        logits[(size_t)(m0 + 3) * 1000 + n] = a3 + bv;
    }
}

__global__ void softmax_kernel(const float* __restrict__ logits, float* __restrict__ pred) {
    __shared__ float red[256];
    const int m = blockIdx.x;
    const int t = threadIdx.x;
    const float* lr = logits + (size_t)m * 1000;
    float mx = -3.4e38f;
    for (int i = t; i < 1000; i += 256) mx = fmaxf(mx, lr[i]);
    red[t] = mx; __syncthreads();
    for (int off = 128; off > 0; off >>= 1) {
        if (t < off) red[t] = fmaxf(red[t], red[t + off]);
        __syncthreads();
    }
    mx = red[0];
    __syncthreads();
    float sm = 0.0f;
    for (int i = t; i < 1000; i += 256) sm += __expf(lr[i] - mx);
    red[t] = sm; __syncthreads();
    for (int off = 128; off > 0; off >>= 1) {
        if (t < off) red[t] += red[t + off];
        __syncthreads();
    }
    const float inv = 1.0f / red[0];
    for (int i = t; i < 1000; i += 256)
        pred[(size_t)m * 1000 + i] = __expf(lr[i] - mx) * inv;
}

extern "C" void kernel_launch(void* const* d_in, const int* in_sizes, int n_in,
                              void* d_out, int out_size, void* d_ws, size_t ws_size,
                              hipStream_t stream) {
    (void)in_sizes; (void)n_in; (void)out_size; (void)ws_size;
    const float* x = (const float*)d_in[0];
    const float* W0[4] = {(const float*)d_in[1], (const float*)d_in[2], (const float*)d_in[3], (const float*)d_in[4]};
    const float* B0[4] = {(const float*)d_in[5], (const float*)d_in[6], (const float*)d_in[7], (const float*)d_in[8]};
    const float* W1[4] = {(const float*)d_in[9], (const float*)d_in[10], (const float*)d_in[11], (const float*)d_in[12]};
    const float* B1[4] = {(const float*)d_in[13], (const float*)d_in[14], (const float*)d_in[15], (const float*)d_in[16]};
    const float* Wc = (const float*)d_in[17];
    const float* bc = (const float*)d_in[18];
    float* out = (float*)d_out;

    char* ws = (char*)d_ws;
    size_t off = 0;
    auto alloc = [&](size_t bytes) -> char* {
        char* p = ws + off;
        off += (bytes + 255) & ~(size_t)255;
        return p;
    };
    unsigned short* wt0 = (unsigned short*)alloc((size_t)4 * NHID * 1536 * 2);
    unsigned short* wt1 = (unsigned short*)alloc((size_t)4 * NHID * 2048 * 2);
    unsigned short* xb  = (unsigned short*)alloc((size_t)NBATCH * 64 * 512 * 2);
    char* hstates = ws + off;
    unsigned short* h0b = (unsigned short*)alloc((size_t)2 * HSZE * 2);
    unsigned short* h1b = (unsigned short*)alloc((size_t)2 * HSZE * 2);
    size_t hstate_bytes = (size_t)((char*)h1b + (size_t)2 * HSZE * 2 - hstates);
    float* h1f = (float*)alloc((size_t)HSZE * 4);
    unsigned* bar = (unsigned*)alloc(1024);

    hipMemsetAsync(hstates, 0, hstate_bytes, stream);
    hipMemsetAsync(bar, 0, 1024, stream);

    transpose_w_kernel<<<dim3(1536 / 64, 16, 4), 256, 0, stream>>>(
        W0[0], W0[1], W0[2], W0[3], wt0, 1536);
    transpose_w_kernel<<<dim3(2048 / 64, 16, 4), 256, 0, stream>>>(
        W1[0], W1[1], W1[2], W1[3], wt1, 2048);
    cvt_x_frag_kernel<<<dim3(64, 16), 256, 0, stream>>>(x, xb);

    lstm_persist_kernel<<<NBLK, 512, 0, stream>>>(
        wt0, wt1, xb,
        B0[0], B0[1], B0[2], B0[3],
        B1[0], B1[1], B1[2], B1[3],
        h0b, h1b, h1f, bar);

    classifier_kernel<<<dim3(4, 64), 256, 0, stream>>>(h1f, Wc, bc, out);
    softmax_kernel<<<NBATCH, 256, 0, stream>>>(out, out + (size_t)NBATCH * 1000);
}